// Round 4
// baseline (263.887 us; speedup 1.0000x reference)
//
#include <hip/hip_runtime.h>

#define IMG 256
#define FBIG 1e10f
#define EPSA 1e-8f
#define BPAD 1e-4f
#define NSLICE 16
#define PXK 8

// Per-face precomputed record, 64B:
// a: x1,y1, y2-y1, x2-x1   (edge0: w0 numerator)
// b: x2,y2, y0-y2, x0-x2   (edge1)
// c: x0,y0, y1-y0, x1-x0   (edge2)
// d: z0,z1,z2, area(=denom)
struct __align__(16) FRec { float4 a, b, c, d; };

__global__ __launch_bounds__(256) void precompute_kernel(
    const float* __restrict__ verts, const int* __restrict__ faces,
    FRec* __restrict__ rec, int* __restrict__ fids,
    unsigned int* __restrict__ cnt, int V, int F)
{
#pragma clang fp contract(off)
    const int f = blockIdx.x * 256 + threadIdx.x;
    const int b = blockIdx.y;
    if (f >= F) return;
    const float* vb = verts + (size_t)b * V * 3;
    const int i0 = faces[3*f+0], i1 = faces[3*f+1], i2 = faces[3*f+2];
    const float x0 = -vb[3*i0+0], y0 = -vb[3*i0+1], z0 = vb[3*i0+2];
    const float x1 = -vb[3*i1+0], y1 = -vb[3*i1+1], z1 = vb[3*i1+2];
    const float x2 = -vb[3*i2+0], y2 = -vb[3*i2+1], z2 = vb[3*i2+2];
    const float area = (x1 - x0) * (y2 - y0) - (y1 - y0) * (x2 - x0);
    const float zmax = fmaxf(fmaxf(z0, z1), z2);
    if (area > EPSA && zmax >= 0.0f) {
        const unsigned int slot = atomicAdd(&cnt[b], 1u);
        FRec r;
        r.a = make_float4(x1, y1, y2 - y1, x2 - x1);
        r.b = make_float4(x2, y2, y0 - y2, x0 - x2);
        r.c = make_float4(x0, y0, y1 - y0, x1 - x0);
        r.d = make_float4(z0, z1, z2, area);
        rec[(size_t)b * F + slot]  = r;
        fids[(size_t)b * F + slot] = f;
    }
}

#define RL(x) __uint_as_float(__builtin_amdgcn_readlane(__float_as_uint(x), bit))

__global__ __launch_bounds__(256, 4) void raster_kernel(
    const FRec* __restrict__ rec, const int* __restrict__ fids,
    const unsigned int* __restrict__ cnt,
    unsigned long long* __restrict__ zpix, int F)
{
#pragma clang fp contract(off)
    const int b     = blockIdx.y;
    const int slice = blockIdx.z;
    const int reg   = blockIdx.x;          // 0..31: cb = col band (64), rb = row band (32)
    const int cb = reg & 3, rb = reg >> 2;
    const int tid  = threadIdx.x;
    const int w    = tid >> 6;
    const int lane = tid & 63;

    const int col = cb * 64 + lane;
    const int r0  = rb * 32 + w * 8;
    const float px = 1.0f - (2.0f * (float)col + 1.0f) / 256.0f;
    float py[PXK];
    #pragma unroll
    for (int k = 0; k < PXK; ++k)
        py[k] = 1.0f - (2.0f * (float)(r0 + k) + 1.0f) / 256.0f;

    // wave-uniform footprint bounds (px,py decrease with pixel index)
    const float px_hi = 1.0f - (2.0f * (float)(cb * 64) + 1.0f) / 256.0f;
    const float px_lo = 1.0f - (2.0f * (float)(cb * 64 + 63) + 1.0f) / 256.0f;
    const float py_hi = py[0];
    const float py_lo = py[PXK - 1];

    const int n = (int)cnt[b];
    if (n <= 0) return;
    const FRec* rbp = rec  + (size_t)b * F;
    const int*  fbp = fids + (size_t)b * F;

    unsigned long long best[PXK];
    float badj[PXK];
    #pragma unroll
    for (int k = 0; k < PXK; ++k) { best[k] = ~0ULL; badj[k] = FBIG; }

    const int ngroups = (n + NSLICE * 64 - 1) / (NSLICE * 64);
    for (int g = 0; g < ngroups; ++g) {
        int i = (g * NSLICE + slice) * 64 + lane;
        const bool val = i < n;
        const int ic = val ? i : (n - 1);
        const FRec r  = rbp[ic];
        const int fid = fbp[ic];
        // bbox from record: xs = {a.x=x1, b.x=x2, c.x=x0}
        const float xmn = fminf(fminf(r.a.x, r.b.x), r.c.x) - BPAD;
        const float xmx = fmaxf(fmaxf(r.a.x, r.b.x), r.c.x) + BPAD;
        const float ymn = fminf(fminf(r.a.y, r.b.y), r.c.y) - BPAD;
        const float ymx = fmaxf(fmaxf(r.a.y, r.b.y), r.c.y) + BPAD;
        const bool ov = val && (xmn <= px_hi) && (xmx >= px_lo) &&
                               (ymn <= py_hi) && (ymx >= py_lo);
        unsigned long long mask = __ballot(ov);
        while (mask) {
            const int bit = (int)__builtin_ctzll(mask);
            mask &= mask - 1;
            // broadcast face record from lane `bit` (VALU readlane, no LDS)
            const float ax = RL(r.a.x), ay = RL(r.a.y), ady = RL(r.a.z), adx = RL(r.a.w);
            const float bx = RL(r.b.x), by = RL(r.b.y), bdy = RL(r.b.z), bdx = RL(r.b.w);
            const float cx = RL(r.c.x), cy = RL(r.c.y), cdy = RL(r.c.z), cdx = RL(r.c.w);
            const float z0 = RL(r.d.x), z1 = RL(r.d.y), z2 = RL(r.d.z), area = RL(r.d.w);
            const int fs = __builtin_amdgcn_readlane(fid, bit);
            // shared per-lane terms: identical value & rounding as ref's (px-ax)*ady
            const float t0 = (px - ax) * ady;
            const float t1 = (px - bx) * bdy;
            const float t2 = (px - cx) * cdy;
            #pragma unroll
            for (int k = 0; k < PXK; ++k) {
                const float e0 = t0 - (py[k] - ay) * adx;
                const float e1 = t1 - (py[k] - by) * bdx;
                const float e2 = t2 - (py[k] - cy) * cdx;
                const float m  = fminf(fminf(e0, e1), e2);
                // filter-only z estimate (fma ok): zt ~= pz*area, err <= ~2e-6*area
                const float zt = __builtin_fmaf(e2, z2, __builtin_fmaf(e1, z1, e0 * z0));
                const bool pass = (m >= 0.0f) & (zt >= -1e-4f) & (zt <= badj[k] * area);
                if (pass) {
                    // exact path: bit-identical to reference
                    const float w0 = e0 / area;
                    const float w1 = e1 / area;
                    const float w2 = e2 / area;
                    const float pz = (w0 * z0 + w1 * z1) + w2 * z2;
                    if (pz >= 0.0f && pz < FBIG) {
                        const unsigned long long cand =
                            ((unsigned long long)__float_as_uint(pz + 0.0f) << 32) |
                            (unsigned int)fs;
                        if (cand < best[k]) {
                            best[k] = cand;
                            const float bz = __uint_as_float((unsigned int)(best[k] >> 32));
                            badj[k] = bz * 1.00001f + 1e-4f;
                        }
                    }
                }
            }
        }
    }

    const int pixbase = (b * IMG + r0) * IMG + col;
    #pragma unroll
    for (int k = 0; k < PXK; ++k) {
        if (best[k] != ~0ULL) {
            unsigned long long* p = &zpix[pixbase + k * IMG];
            if (best[k] < *p) atomicMin(p, best[k]);
        }
    }
}

__global__ __launch_bounds__(256) void resolve_kernel(
    const float* __restrict__ verts, const int* __restrict__ faces,
    const unsigned long long* __restrict__ zpix,
    float* __restrict__ out, int B, int V, int F)
{
#pragma clang fp contract(off)
    const int idx = blockIdx.x * 256 + threadIdx.x;
    if (idx >= B * IMG * IMG) return;
    const int b   = idx / (IMG * IMG);
    const int p   = idx - b * (IMG * IMG);
    const int row = p >> 8, col = p & 255;

    const unsigned long long v = zpix[idx];
    float p2f = -1.0f, o0 = -1.0f, o1 = -1.0f, o2 = -1.0f;
    if (v != ~0ULL) {
        const int fid = (int)(v & 0xFFFFFFFFu);
        const float* vb = verts + (size_t)b * V * 3;
        const int i0 = faces[3*fid+0], i1 = faces[3*fid+1], i2 = faces[3*fid+2];
        const float x0 = -vb[3*i0+0], y0 = -vb[3*i0+1];
        const float x1 = -vb[3*i1+0], y1 = -vb[3*i1+1];
        const float x2 = -vb[3*i2+0], y2 = -vb[3*i2+1];
        const float area = (x1 - x0) * (y2 - y0) - (y1 - y0) * (x2 - x0);
        const float px = 1.0f - (2.0f * (float)col + 1.0f) / 256.0f;
        const float py = 1.0f - (2.0f * (float)row + 1.0f) / 256.0f;
        const float e0 = (px - x1) * (y2 - y1) - (py - y1) * (x2 - x1);
        const float e1 = (px - x2) * (y0 - y2) - (py - y2) * (x0 - x2);
        const float e2 = (px - x0) * (y1 - y0) - (py - y0) * (x1 - x0);
        o0 = e0 / area; o1 = e1 / area; o2 = e2 / area;
        p2f = (float)(fid + b * F);
    }
    out[idx] = p2f;
    const size_t boff = (size_t)B * IMG * IMG + (size_t)idx * 3;
    out[boff + 0] = o0; out[boff + 1] = o1; out[boff + 2] = o2;
}

extern "C" void kernel_launch(void* const* d_in, const int* in_sizes, int n_in,
                              void* d_out, int out_size, void* d_ws, size_t ws_size,
                              hipStream_t stream) {
    const float* vertices = (const float*)d_in[0];
    const int*   faces    = (const int*)d_in[1];
    float* out = (float*)d_out;

    const int F = in_sizes[1] / 3;
    const int B = 2;
    const int V = in_sizes[0] / (3 * B);

    // ws layout
    char* w = (char*)d_ws;
    unsigned int* cnt = (unsigned int*)w;                       // B counters
    size_t off = 256;
    FRec* rec = (FRec*)(w + off);          off += (size_t)B * F * sizeof(FRec);
    int* fids = (int*)(w + off);           off += (size_t)B * F * sizeof(int);
    off = (off + 255) & ~(size_t)255;
    unsigned long long* zpix = (unsigned long long*)(w + off);
    const size_t npix = (size_t)B * IMG * IMG;

    hipMemsetAsync(cnt, 0, B * sizeof(unsigned int), stream);
    hipMemsetAsync(zpix, 0xFF, npix * 8, stream);

    dim3 gpre((F + 255) / 256, B);
    precompute_kernel<<<gpre, 256, 0, stream>>>(vertices, faces, rec, fids, cnt, V, F);

    dim3 gras(32, B, NSLICE);
    raster_kernel<<<gras, 256, 0, stream>>>(rec, fids, cnt, zpix, F);

    dim3 gres((unsigned)((npix + 255) / 256));
    resolve_kernel<<<gres, 256, 0, stream>>>(vertices, faces, zpix, out, B, V, F);
}

// Round 5
// 168.830 us; speedup vs baseline: 1.5630x; 1.5630x over previous
//
#include <hip/hip_runtime.h>

#define IMG 256
#define FBIG 1e10f
#define EPSA 1e-8f
#define BPAD 1e-4f
#define NSLICE 16
#define CHUNK 128
#define PXK 4

// Per-face precomputed record, 64B:
// a: x1,y1, y2-y1, x2-x1   (edge0: w0 numerator)
// b: x2,y2, y0-y2, x0-x2   (edge1)
// c: x0,y0, y1-y0, x1-x0   (edge2)
// d: z0,z1,z2, area(=denom)
struct __align__(16) FRec { float4 a, b, c, d; };

__global__ __launch_bounds__(256) void precompute_kernel(
    const float* __restrict__ verts, const int* __restrict__ faces,
    FRec* __restrict__ rec, int* __restrict__ fids,
    unsigned int* __restrict__ cnt, int V, int F)
{
#pragma clang fp contract(off)
    const int f = blockIdx.x * 256 + threadIdx.x;
    const int b = blockIdx.y;
    if (f >= F) return;
    const float* vb = verts + (size_t)b * V * 3;
    const int i0 = faces[3*f+0], i1 = faces[3*f+1], i2 = faces[3*f+2];
    const float x0 = -vb[3*i0+0], y0 = -vb[3*i0+1], z0 = vb[3*i0+2];
    const float x1 = -vb[3*i1+0], y1 = -vb[3*i1+1], z1 = vb[3*i1+2];
    const float x2 = -vb[3*i2+0], y2 = -vb[3*i2+1], z2 = vb[3*i2+2];
    const float area = (x1 - x0) * (y2 - y0) - (y1 - y0) * (x2 - x0);
    const float zmax = fmaxf(fmaxf(z0, z1), z2);
    if (area > EPSA && zmax >= 0.0f) {
        const unsigned int slot = atomicAdd(&cnt[b], 1u);
        FRec r;
        r.a = make_float4(x1, y1, y2 - y1, x2 - x1);
        r.b = make_float4(x2, y2, y0 - y2, x0 - x2);
        r.c = make_float4(x0, y0, y1 - y0, x1 - x0);
        r.d = make_float4(z0, z1, z2, area);
        rec[(size_t)b * F + slot]  = r;
        fids[(size_t)b * F + slot] = f;
    }
}

__global__ __launch_bounds__(256) void raster_kernel(
    const FRec* __restrict__ rec, const int* __restrict__ fids,
    const unsigned int* __restrict__ cnt,
    unsigned long long* __restrict__ zpix, int F)
{
#pragma clang fp contract(off)
    __shared__ float4 s_rec[CHUNK][5];   // [0..3]=a,b,c,d  [4].x=fid bits (80B stride)
    __shared__ float  s_bb[4][CHUNK];    // transposed bbox: stride-1 reads

    const int b      = blockIdx.y;
    const int slice  = blockIdx.z;
    const int region = blockIdx.x;       // 0..63 : 8x8 grid of 32x32-px regions
    const int rg_r = (region >> 3) * 32;
    const int rg_c = (region & 7) * 32;
    const int tid  = threadIdx.x;
    const int wv   = tid >> 6;
    const int lane = tid & 63;
    const int tile_r = rg_r + (wv >> 1) * 16;   // wave owns a 16x16 tile
    const int tile_c = rg_c + (wv & 1) * 16;
    const int col  = tile_c + (lane & 15);
    const int row0 = tile_r + (lane >> 4) * 4;  // lane owns 4 consecutive rows

    const float px = 1.0f - (2.0f * (float)col + 1.0f) / 256.0f;
    float py[PXK];
    #pragma unroll
    for (int k = 0; k < PXK; ++k)
        py[k] = 1.0f - (2.0f * (float)(row0 + k) + 1.0f) / 256.0f;

    // wave-uniform footprint bounds (px,py decrease with pixel index)
    const float px_hi = 1.0f - (2.0f * (float)tile_c + 1.0f) / 256.0f;
    const float px_lo = 1.0f - (2.0f * (float)(tile_c + 15) + 1.0f) / 256.0f;
    const float py_hi = 1.0f - (2.0f * (float)tile_r + 1.0f) / 256.0f;
    const float py_lo = 1.0f - (2.0f * (float)(tile_r + 15) + 1.0f) / 256.0f;

    const int n   = (int)cnt[b];
    const int nch = (n + CHUNK - 1) / CHUNK;
    const FRec* rbp = rec  + (size_t)b * F;
    const int*  fbp = fids + (size_t)b * F;

    unsigned long long best[PXK];
    float badj[PXK];
    #pragma unroll
    for (int k = 0; k < PXK; ++k) { best[k] = ~0ULL; badj[k] = FBIG; }

    for (int c = slice; c < nch; c += NSLICE) {
        __syncthreads();
        if (tid < CHUNK) {
            const int f = c * CHUNK + tid;
            if (f < n) {
                const FRec r = rbp[f];
                s_rec[tid][0] = r.a;
                s_rec[tid][1] = r.b;
                s_rec[tid][2] = r.c;
                s_rec[tid][3] = r.d;
                s_rec[tid][4] = make_float4(__int_as_float(fbp[f]), 0.f, 0.f, 0.f);
                // bbox: xs = {a.x=x1, b.x=x2, c.x=x0}
                s_bb[0][tid] = fminf(fminf(r.a.x, r.b.x), r.c.x) - BPAD;
                s_bb[1][tid] = fmaxf(fmaxf(r.a.x, r.b.x), r.c.x) + BPAD;
                s_bb[2][tid] = fminf(fminf(r.a.y, r.b.y), r.c.y) - BPAD;
                s_bb[3][tid] = fmaxf(fmaxf(r.a.y, r.b.y), r.c.y) + BPAD;
            } else {
                s_bb[0][tid] =  4e9f; s_bb[1][tid] = -4e9f;
                s_bb[2][tid] =  4e9f; s_bb[3][tid] = -4e9f;
            }
        }
        __syncthreads();

        #pragma unroll
        for (int g = 0; g < CHUNK / 64; ++g) {
            const int fl = g * 64 + lane;
            const bool ov = (s_bb[0][fl] <= px_hi) && (s_bb[1][fl] >= px_lo) &&
                            (s_bb[2][fl] <= py_hi) && (s_bb[3][fl] >= py_lo);
            unsigned long long mask = __ballot(ov);
            while (mask) {
                const int bit = (int)__builtin_ctzll(mask);
                mask &= mask - 1;
                const int idx = g * 64 + bit;            // wave-uniform
                const float4 ra = s_rec[idx][0];         // broadcast b128 reads
                const float4 rb = s_rec[idx][1];
                const float4 rc = s_rec[idx][2];
                const float4 rd = s_rec[idx][3];
                const int    fs = __float_as_int(s_rec[idx][4].x);
                // shared per-lane terms: same value & rounding as ref's (px-x)*dy
                const float t0 = (px - ra.x) * ra.z;
                const float t1 = (px - rb.x) * rb.z;
                const float t2 = (px - rc.x) * rc.z;
                #pragma unroll
                for (int k = 0; k < PXK; ++k) {
                    const float e0 = t0 - (py[k] - ra.y) * ra.w;
                    const float e1 = t1 - (py[k] - rb.y) * rb.w;
                    const float e2 = t2 - (py[k] - rc.y) * rc.w;
                    const float m  = fminf(fminf(e0, e1), e2);
                    // filter-only z estimate (fma ok): zt ~= pz*area, |err| <~ 7e-7*area
                    const float zt = __builtin_fmaf(e2, rd.z,
                                      __builtin_fmaf(e1, rd.y, e0 * rd.x));
                    if (m >= 0.0f && zt >= -1e-4f && zt <= badj[k] * rd.w) {
                        // exact path: bit-identical to reference
                        const float w0 = e0 / rd.w;
                        const float w1 = e1 / rd.w;
                        const float w2 = e2 / rd.w;
                        const float pz = (w0 * rd.x + w1 * rd.y) + w2 * rd.z;
                        if (pz >= 0.0f && pz < FBIG) {
                            const unsigned long long cand =
                                ((unsigned long long)__float_as_uint(pz + 0.0f) << 32) |
                                (unsigned int)fs;
                            if (cand < best[k]) {
                                best[k] = cand;
                                const float bz = __uint_as_float((unsigned int)(best[k] >> 32));
                                badj[k] = bz * 1.00001f + 1e-4f;
                            }
                        }
                    }
                }
            }
        }
    }

    #pragma unroll
    for (int k = 0; k < PXK; ++k) {
        if (best[k] != ~0ULL) {
            unsigned long long* p = &zpix[(b * IMG + row0 + k) * IMG + col];
            if (best[k] < *p) atomicMin(p, best[k]);
        }
    }
}

__global__ __launch_bounds__(256) void resolve_kernel(
    const float* __restrict__ verts, const int* __restrict__ faces,
    const unsigned long long* __restrict__ zpix,
    float* __restrict__ out, int B, int V, int F)
{
#pragma clang fp contract(off)
    const int idx = blockIdx.x * 256 + threadIdx.x;
    if (idx >= B * IMG * IMG) return;
    const int b   = idx / (IMG * IMG);
    const int p   = idx - b * (IMG * IMG);
    const int row = p >> 8, col = p & 255;

    const unsigned long long v = zpix[idx];
    float p2f = -1.0f, o0 = -1.0f, o1 = -1.0f, o2 = -1.0f;
    if (v != ~0ULL) {
        const int fid = (int)(v & 0xFFFFFFFFu);
        const float* vb = verts + (size_t)b * V * 3;
        const int i0 = faces[3*fid+0], i1 = faces[3*fid+1], i2 = faces[3*fid+2];
        const float x0 = -vb[3*i0+0], y0 = -vb[3*i0+1];
        const float x1 = -vb[3*i1+0], y1 = -vb[3*i1+1];
        const float x2 = -vb[3*i2+0], y2 = -vb[3*i2+1];
        const float area = (x1 - x0) * (y2 - y0) - (y1 - y0) * (x2 - x0);
        const float px = 1.0f - (2.0f * (float)col + 1.0f) / 256.0f;
        const float py = 1.0f - (2.0f * (float)row + 1.0f) / 256.0f;
        const float e0 = (px - x1) * (y2 - y1) - (py - y1) * (x2 - x1);
        const float e1 = (px - x2) * (y0 - y2) - (py - y2) * (x0 - x2);
        const float e2 = (px - x0) * (y1 - y0) - (py - y0) * (x1 - x0);
        o0 = e0 / area; o1 = e1 / area; o2 = e2 / area;
        p2f = (float)(fid + b * F);
    }
    out[idx] = p2f;
    const size_t boff = (size_t)B * IMG * IMG + (size_t)idx * 3;
    out[boff + 0] = o0; out[boff + 1] = o1; out[boff + 2] = o2;
}

extern "C" void kernel_launch(void* const* d_in, const int* in_sizes, int n_in,
                              void* d_out, int out_size, void* d_ws, size_t ws_size,
                              hipStream_t stream) {
    const float* vertices = (const float*)d_in[0];
    const int*   faces    = (const int*)d_in[1];
    float* out = (float*)d_out;

    const int F = in_sizes[1] / 3;
    const int B = 2;
    const int V = in_sizes[0] / (3 * B);

    // ws layout
    char* w = (char*)d_ws;
    unsigned int* cnt = (unsigned int*)w;                       // B counters
    size_t off = 256;
    FRec* rec = (FRec*)(w + off);          off += (size_t)B * F * sizeof(FRec);
    int* fids = (int*)(w + off);           off += (size_t)B * F * sizeof(int);
    off = (off + 255) & ~(size_t)255;
    unsigned long long* zpix = (unsigned long long*)(w + off);
    const size_t npix = (size_t)B * IMG * IMG;

    hipMemsetAsync(cnt, 0, B * sizeof(unsigned int), stream);
    hipMemsetAsync(zpix, 0xFF, npix * 8, stream);

    dim3 gpre((F + 255) / 256, B);
    precompute_kernel<<<gpre, 256, 0, stream>>>(vertices, faces, rec, fids, cnt, V, F);

    dim3 gras(64, B, NSLICE);
    raster_kernel<<<gras, 256, 0, stream>>>(rec, fids, cnt, zpix, F);

    dim3 gres((unsigned)((npix + 255) / 256));
    resolve_kernel<<<gres, 256, 0, stream>>>(vertices, faces, zpix, out, B, V, F);
}